// Round 1
// 54.699 us; speedup vs baseline: 1.0403x; 1.0403x over previous
//
#include <hip/hip_runtime.h>
#include <math.h>

// v15 = v14 with two levers:
//  (1) O(n) transfer DP: the v14 per-k backward sweep is E_k = w^T (T_0..T_{k-1}) s_k.
//      All k share the same left product, so maintain the row-vector prefix
//      r_k = w^T T_0 ... T_{k-1}  (5 FMAs/step) and accumulate E += r_k . s_k.
//      Exact reassociation of v14's verified DP (v11 row was identically 0).
//  (2) HW transcendentals: __sincosf -> v_sin_f32/v_cos_f32 (~4 insts vs ~30 libm).
//      Angles are O(1) rad; hw trig error ~1e-6 << pass margin (absmax 0.0039).
//  (3) x row loaded as 5x float2 (rows are 8B-aligned).
// Dtypes (proven): x (128,10) fp32, w (64,10,2) fp32, out (64,128) fp32.

__global__ __launch_bounds__(128) void qnn_closed_v15(const float* __restrict__ gx,
                                                      const float* __restrict__ gw,
                                                      float* __restrict__ gout) {
    __shared__ float wc0[10], ws0[10], wc1[10], ws1[10];
    const int b = (int)threadIdx.x;   // batch 0..127
    const int f = (int)blockIdx.x;    // feature 0..63

    if (b < 20) {
        const int q = b % 10;
        const int l = b / 10;
        const float a = gw[(f * 10 + q) * 2 + l];
        float s, c;
        __sincosf(a, &s, &c);
        if (l == 0) { wc0[q] = c; ws0[q] = s; }
        else        { wc1[q] = c; ws1[q] = s; }
    }
    __syncthreads();

    // x row for this batch: 10 floats, 8B-aligned -> 5x float2
    float xa[10];
    {
        const float2* gx2 = reinterpret_cast<const float2*>(gx + b * 10);
        #pragma unroll
        for (int i = 0; i < 5; ++i) {
            const float2 v = gx2[i];
            xa[2 * i]     = v.x;
            xa[2 * i + 1] = v.y;
        }
    }

    // product-state moments for merged theta_q = x[b,q] + w[f,q,0]:
    //   z[q] = cos(theta), xv[q] = sin(theta)  (angle addition, 2 FMA each)
    float z[10], xv[10];
    #pragma unroll
    for (int q = 0; q < 10; ++q) {
        float sx, cx;
        __sincosf(xa[q], &sx, &cx);
        z[q]  = cx * wc0[q] - sx * ws0[q];
        xv[q] = sx * wc0[q] + cx * ws0[q];
    }

    // O(n) prefix form of the 4-state transfer DP.
    // Row vector r = (r0, r1, r2) starts at w = (z[0], 1, xv[0]);
    // per k: E += r . s_k with s_k = (cc_k, 0, -ss_k * f_k), f_k = xv[k+1] (or 1 at k=9);
    // then r <- r T_k:
    //   r0' = cc_k * z[k+1] * r1
    //   r1' = cc_k * r0 - ss_k * xv[k+1] * r2
    //   r2' = xv[k+1] * (cc_k * r0) - ss_k * r2
    float r0 = z[0], r1 = 1.0f, r2 = xv[0];
    float E = 0.0f;
    #pragma unroll
    for (int k = 0; k < 10; ++k) {
        const float cck = wc1[k];
        const float ssk = ws1[k];
        const float fk = (k < 9) ? xv[k + 1] : 1.0f;
        E += cck * r0 - ssk * fk * r2;
        if (k < 9) {
            const float zk = z[k + 1];
            const float xk = xv[k + 1];
            const float t  = cck * r0;
            const float u  = ssk * r2;
            const float n0 = cck * zk * r1;
            r1 = t - xk * u;
            r2 = xk * t - u;
            r0 = n0;
        }
    }

    gout[f * 128 + b] = E;
}

extern "C" void kernel_launch(void* const* d_in, const int* in_sizes, int n_in,
                              void* d_out, int out_size, void* d_ws, size_t ws_size,
                              hipStream_t stream) {
    const float* x = (const float*)d_in[0];   // (128, 10) fp32
    const float* w = (const float*)d_in[1];   // (64, 10, 2) fp32
    float* out = (float*)d_out;               // (64, 128) fp32

    // one block per feature, one thread per batch
    hipLaunchKernelGGL(qnn_closed_v15, dim3(64), dim3(128), 0, stream, x, w, out);
}